// Round 6
// baseline (547.084 us; speedup 1.0000x reference)
//
#include <hip/hip_runtime.h>

#define CD 768
#define NHEAD 12
#define DH 64
#define BSZ 2
#define NM_ 4096
#define NX_ 16384
#define EPSF 1e-6f
#define KSTR 1536   // ushort stride of in-place bf16 rows inside an fp32 buffer
#define KVCH 32     // split-K chunks for kv partials

using bf16x8 = __attribute__((ext_vector_type(8))) short;
using f32x4  = __attribute__((ext_vector_type(4))) float;

__device__ inline unsigned short bf16r(float f) {
  union { float f; unsigned u; } un; un.f = f;
  unsigned u = un.u;
  u += 0x7fffu + ((u >> 16) & 1u);
  return (unsigned short)(u >> 16);
}
__device__ inline float b2f(unsigned short u) {
  union { unsigned u; float f; } x; x.u = ((unsigned)u) << 16; return x.f;
}
__device__ inline float asf(unsigned u) {
  union { unsigned u; float f; } x; x.u = u; return x.f;
}
// async global->LDS, 16B per lane; LDS dest = wave-uniform base + lane*16
__device__ inline void gl2lds16(const void* g, void* l) {
  __builtin_amdgcn_global_load_lds(
      (const __attribute__((address_space(1))) void*)g,
      (__attribute__((address_space(3))) void*)l, 16, 0, 0);
}

// ---- prep: 4 weight matrices fp32->bf16 + softplus(scale), ONE dispatch ----
__global__ __launch_bounds__(256) void prep_k(const float* __restrict__ w0, const float* __restrict__ w1,
                                              const float* __restrict__ w2, const float* __restrict__ w3,
                                              const float* __restrict__ scale,
                                              unsigned short* __restrict__ o0, unsigned short* __restrict__ o1,
                                              unsigned short* __restrict__ o2, unsigned short* __restrict__ o3,
                                              float* __restrict__ sp) {
  int bx = blockIdx.x;
  if (bx < 2304) {                    // 4 matrices x 576 blocks x 256 float4
    int m = bx / 576;
    int i = (bx % 576) * 256 + threadIdx.x;
    const float* w = m == 0 ? w0 : m == 1 ? w1 : m == 2 ? w2 : w3;
    unsigned short* o = m == 0 ? o0 : m == 1 ? o1 : m == 2 ? o2 : o3;
    float4 v = ((const float4*)w)[i];
    ushort4 u; u.x = bf16r(v.x); u.y = bf16r(v.y); u.z = bf16r(v.z); u.w = bf16r(v.w);
    ((ushort4*)o)[i] = u;
  } else {
    int i = (bx - 2304) * 256 + threadIdx.x;
    if (i < CD) sp[i] = log1pf(expf(scale[i]));
  }
}

// ---- fp32 -> bf16 bulk convert: thread i converts 8 elements (32B in, 16B out)
__global__ __launch_bounds__(256) void cvt_k(const float* __restrict__ s,
                                             unsigned short* __restrict__ d, int n8) {
  int i = blockIdx.x * 256 + threadIdx.x;
  if (i >= n8) return;
  const float4* sp = (const float4*)s;
  float4 f0 = sp[(size_t)i * 2], f1 = sp[(size_t)i * 2 + 1];
  unsigned short u[8];
  u[0] = bf16r(f0.x); u[1] = bf16r(f0.y); u[2] = bf16r(f0.z); u[3] = bf16r(f0.w);
  u[4] = bf16r(f1.x); u[5] = bf16r(f1.y); u[6] = bf16r(f1.z); u[7] = bf16r(f1.w);
  *(int4*)(d + (size_t)i * 8) = *(int4*)u;
}

// ------- 128x128-tile GEMM (bf16 A): C[M,N] = A[M,K] @ B[N,K]^T (+bias) -----
template<int OUTBF>
__global__ __launch_bounds__(256) void gemm128(const unsigned short* __restrict__ A,
                                               const unsigned short* __restrict__ B,
                                               void* __restrict__ Cv,
                                               const float* __restrict__ bias,
                                               int M, int N, int K) {
  __shared__ __align__(16) unsigned short As[128 * 32];
  __shared__ __align__(16) unsigned short Bs[128 * 32];
  const int m0 = blockIdx.x * 128, n0 = blockIdx.y * 128;
  const int tid = threadIdx.x, wave = tid >> 6, lane = tid & 63;
  const int quad = lane >> 4, l16 = lane & 15;
  const int wm = (wave >> 1) * 64, wn = (wave & 1) * 64;
  const int srow = lane >> 2, scol = (lane & 3) * 8;  // gl2lds: 16 rows/chunk, 4 lanes/row
  f32x4 acc[4][4] = {};
  for (int k0 = 0; k0 < K; k0 += 32) {
    __syncthreads();
    #pragma unroll
    for (int c2 = 0; c2 < 2; ++c2) {
      int ch = wave * 2 + c2;
      gl2lds16(A + (size_t)(m0 + ch * 16 + srow) * K + k0 + scol, (void*)(As + ch * 512));
      gl2lds16(B + (size_t)(n0 + ch * 16 + srow) * K + k0 + scol, (void*)(Bs + ch * 512));
    }
    __syncthreads();
    bf16x8 a[4], bb[4];
    #pragma unroll
    for (int t = 0; t < 4; ++t) {
      a[t]  = *(const bf16x8*)(As + (wm + t * 16 + l16) * 32 + quad * 8);
      bb[t] = *(const bf16x8*)(Bs + (wn + t * 16 + l16) * 32 + quad * 8);
    }
    #pragma unroll
    for (int tm = 0; tm < 4; ++tm)
      #pragma unroll
      for (int tn = 0; tn < 4; ++tn)
        acc[tm][tn] = __builtin_amdgcn_mfma_f32_16x16x32_bf16(a[tm], bb[tn], acc[tm][tn], 0, 0, 0);
  }
  // D layout: col = lane&15, row = quad*4 + r  [m89/m91 verified]
  #pragma unroll
  for (int tm = 0; tm < 4; ++tm)
    #pragma unroll
    for (int tn = 0; tn < 4; ++tn) {
      const int col = n0 + wn + tn * 16 + l16;
      const float bv = bias ? bias[col] : 0.f;
      #pragma unroll
      for (int r = 0; r < 4; ++r) {
        const int row = m0 + wm + tm * 16 + quad * 4 + r;
        float v = acc[tm][tn][r] + bv;
        if (OUTBF) ((unsigned short*)Cv)[(size_t)row * N + col] = bf16r(v);
        else       ((float*)Cv)[(size_t)row * N + col] = v;
      }
    }
}

// ====== 256x256 8-phase GEMM, K=768 (m201 port): C = A[M,768] @ B[768,768]^T =
// 512 thr = 8 waves (2M x 4N); per-wave 128x64 out, acc[8][4] f32x4.
// 12 K-tiles of BK=64; double-buffered LDS [2 buf][2 kh][256 rows][32 cols]
// (kh-major: each half-tile = contiguous 16 KB = 2 gl2lds/thread).
// Per tile 4 phases {vmcnt(4)@even -> barrier -> ds_read 8|4 -> stage 1 HT of
// tile T+1 into buf^1 -> setprio MFMA x16 -> barrier}. Wait induction: entering
// each tile exactly next tile's 4 HTs (8 loads) in flight; vmcnt(4) retires
// precisely the kh-half about to be read. Never drains mid-loop (T3+T4).
// Swizzle: physical chunk = quad ^ (l16&3), source pre-swizzled (rule #21);
// with 64B kh-row stride a wave's 64 b128 lanes cover all 32 banks uniformly.
template<int OUTBF>
__global__ __launch_bounds__(512) void gemm8p(const unsigned short* __restrict__ A,
                                              const unsigned short* __restrict__ B,
                                              void* __restrict__ Cv,
                                              const float* __restrict__ bias,
                                              int M, int N) {
  __shared__ __align__(16) unsigned short As[2 * 2 * 256 * 32];  // 64 KiB
  __shared__ __align__(16) unsigned short Bs[2 * 2 * 256 * 32];  // 64 KiB
  const int m0 = blockIdx.x * 256, n0 = blockIdx.y * 256;
  const int tid = threadIdx.x, w = tid >> 6, lane = tid & 63;
  const int quad = lane >> 4, l16 = lane & 15;
  const int wm = (w >> 2) * 128, wn = (w & 3) * 64;
  const int rswz = (quad ^ (l16 & 3)) * 8;                 // frag-read chunk swizzle
  const int srow0 = (w * 2) * 16 + (lane >> 2);            // staging row, instr j=0
  const int scol  = ((lane & 3) ^ ((lane >> 2) & 3)) * 8;  // pre-swizzled src chunk

  auto stage_ht = [&](int Tn, int ht) {   // ht: 0=A-kh0 1=B-kh0 2=A-kh1 3=B-kh1
    const int kh = ht >> 1;
    const int buf = Tn & 1;
    const unsigned short* G = (ht & 1) ? B : A;
    const int base = (ht & 1) ? n0 : m0;
    unsigned short* L = ((ht & 1) ? Bs : As) + buf * 16384 + kh * 8192;
    const int colg = Tn * 64 + kh * 32 + scol;
    gl2lds16(G + (size_t)(base + srow0) * 768 + colg,      (void*)(L + (w * 2) * 512));
    gl2lds16(G + (size_t)(base + srow0 + 16) * 768 + colg, (void*)(L + (w * 2 + 1) * 512));
  };

  f32x4 acc[8][4] = {};
  // prologue: tile 0's four half-tiles (8 loads/thread in flight)
  stage_ht(0, 0); stage_ht(0, 1); stage_ht(0, 2); stage_ht(0, 3);

  for (int T = 0; T < 12; ++T) {
    const int buf = T & 1;
    const unsigned short* ab = As + buf * 16384;
    const unsigned short* bb = Bs + buf * 16384;
    #pragma unroll
    for (int kh = 0; kh < 2; ++kh) {
      const unsigned short* abk = ab + kh * 8192;
      const unsigned short* bbk = bb + kh * 8192;
      // -------- even phase: kh, m-half 0 (8 ds_read, 16 MFMA) --------
      if (T < 11 || kh == 0) asm volatile("s_waitcnt vmcnt(4)");
      else                   asm volatile("s_waitcnt vmcnt(0)");
      __builtin_amdgcn_s_barrier();          // staged data visible to ALL waves
      __builtin_amdgcn_sched_barrier(0);     // pin ds_reads below the barrier
      bf16x8 av[4], bv[4];
      #pragma unroll
      for (int nf = 0; nf < 4; ++nf)
        bv[nf] = *(const bf16x8*)(bbk + (wn + nf * 16 + l16) * 32 + rswz);
      #pragma unroll
      for (int f = 0; f < 4; ++f)
        av[f] = *(const bf16x8*)(abk + (wm + f * 16 + l16) * 32 + rswz);
      if (T < 11) stage_ht(T + 1, kh * 2);         // HT(A, kh) of next tile
      __builtin_amdgcn_s_setprio(1);
      #pragma unroll
      for (int mf = 0; mf < 4; ++mf)
        #pragma unroll
        for (int nf = 0; nf < 4; ++nf)
          acc[mf][nf] = __builtin_amdgcn_mfma_f32_16x16x32_bf16(av[mf], bv[nf], acc[mf][nf], 0, 0, 0);
      __builtin_amdgcn_s_setprio(0);
      __builtin_amdgcn_s_barrier();
      // -------- odd phase: kh, m-half 1 (4 ds_read, B frags reused) --------
      bf16x8 aw[4];
      #pragma unroll
      for (int f = 0; f < 4; ++f)
        aw[f] = *(const bf16x8*)(abk + (wm + 64 + f * 16 + l16) * 32 + rswz);
      if (T < 11) stage_ht(T + 1, kh * 2 + 1);     // HT(B, kh) of next tile
      __builtin_amdgcn_s_setprio(1);
      #pragma unroll
      for (int mf = 0; mf < 4; ++mf)
        #pragma unroll
        for (int nf = 0; nf < 4; ++nf)
          acc[4 + mf][nf] = __builtin_amdgcn_mfma_f32_16x16x32_bf16(aw[mf], bv[nf], acc[4 + mf][nf], 0, 0, 0);
      __builtin_amdgcn_s_setprio(0);
      __builtin_amdgcn_s_barrier();
    }
  }
  // D layout: col = lane&15, row = quad*4 + r  [m89/m91 verified]
  #pragma unroll
  for (int mf = 0; mf < 8; ++mf)
    #pragma unroll
    for (int nf = 0; nf < 4; ++nf) {
      const int col = n0 + wn + nf * 16 + l16;
      const float bvl = bias ? bias[col] : 0.f;
      #pragma unroll
      for (int r = 0; r < 4; ++r) {
        const int row = m0 + wm + mf * 16 + quad * 4 + r;
        float v = acc[mf][nf][r] + bvl;
        if (OUTBF) ((unsigned short*)Cv)[(size_t)row * N + col] = bf16r(v);
        else       ((float*)Cv)[(size_t)row * N + col] = v;
      }
    }
}

// ------- _process: read fp32 row, write bf16 row IN-PLACE (stride KSTR) -------
__global__ __launch_bounds__(256) void process_rows(float* __restrict__ X,
                                                    const float* __restrict__ sp) {
  const int row = blockIdx.x;
  const int tid = threadIdx.x;
  float* xr = X + (size_t)row * CD;
  float tv[3];
  float n2 = 0.f, m2 = 0.f;
  #pragma unroll
  for (int i = 0; i < 3; ++i) {
    int c = tid + i * 256;
    float t = fmaxf(xr[c], 0.f) + EPSF;
    t = t / sp[c];
    tv[i] = t;
    float t2 = t * t;
    n2 += t2;
    float p = t2 * t;
    m2 += p * p;
  }
  #pragma unroll
  for (int off = 32; off; off >>= 1) {
    n2 += __shfl_down(n2, off, 64);
    m2 += __shfl_down(m2, off, 64);
  }
  __shared__ float rn[4], rm[4];
  if ((tid & 63) == 0) { rn[tid >> 6] = n2; rm[tid >> 6] = m2; }
  __syncthreads();   // also orders: all global reads done before bf16 overwrite
  float N2 = rn[0] + rn[1] + rn[2] + rn[3];
  float M2 = rm[0] + rm[1] + rm[2] + rm[3];
  float factor = sqrtf(N2 / M2);   // = ||t|| / ||t^3||
  unsigned short* xo = (unsigned short*)xr;
  #pragma unroll
  for (int i = 0; i < 3; ++i) {
    int c = tid + i * 256;
    float t = tv[i];
    xo[c] = bf16r(t * t * t * factor);
  }
}

// ---- kv partials: kvp[ch][bh][d][e] = sum_{n in chunk} k[n,d]*v[n,e] --------
__global__ __launch_bounds__(256) void kv_part_k(const unsigned short* __restrict__ Kp,
                                                 const unsigned short* __restrict__ Vp,
                                                 float* __restrict__ kvp,
                                                 float* __restrict__ kmp) {
  const int bh = blockIdx.x, chunk = blockIdx.y;
  const int b = bh / NHEAD, h = bh % NHEAD;
  const int n0 = chunk * 128;
  __shared__ __align__(16) unsigned short ks[128 * 72];
  __shared__ __align__(16) unsigned short vs[128 * 72];
  const int tid = threadIdx.x;
  #pragma unroll
  for (int it = 0; it < 4; ++it) {
    int g = it * 256 + tid;            // 1024 groups of 8 elements per tile
    int row = g >> 3, c8 = (g & 7) * 8;
    int4 ka = *(const int4*)(Kp + ((size_t)(n0 + row) * BSZ + b) * KSTR + h * 64 + c8);
    int4 va = *(const int4*)(Vp + ((size_t)(n0 + row) * BSZ + b) * CD + h * 64 + c8);
    *(int4*)(ks + row * 72 + c8) = ka;
    *(int4*)(vs + row * 72 + c8) = va;
  }
  __syncthreads();
  const int d0 = (tid >> 4) * 4, e0 = (tid & 15) * 4;
  float acc[4][4] = {};
  #pragma unroll 4
  for (int n = 0; n < 128; ++n) {
    ushort4 kd = *(const ushort4*)(ks + n * 72 + d0);
    ushort4 ve = *(const ushort4*)(vs + n * 72 + e0);
    float kf[4] = {b2f(kd.x), b2f(kd.y), b2f(kd.z), b2f(kd.w)};
    float vf[4] = {b2f(ve.x), b2f(ve.y), b2f(ve.z), b2f(ve.w)};
    #pragma unroll
    for (int i = 0; i < 4; ++i)
      #pragma unroll
      for (int j = 0; j < 4; ++j) acc[i][j] += kf[i] * vf[j];
  }
  float* outp = kvp + ((size_t)chunk * 24 + bh) * 4096;
  #pragma unroll
  for (int i = 0; i < 4; ++i) {
    float4 o; o.x = acc[i][0]; o.y = acc[i][1]; o.z = acc[i][2]; o.w = acc[i][3];
    *(float4*)(outp + (d0 + i) * 64 + e0) = o;
  }
  if (tid < 64) {
    float s = 0.f;
    for (int n = 0; n < 128; ++n) s += b2f(ks[n * 72 + tid]);
    kmp[((size_t)chunk * 24 + bh) * 64 + tid] = s;
  }
}

// ---- reduce partials -> kvT[bh][e][d] bf16 (+1/Nm) and km[b][c] fp32 --------
__global__ __launch_bounds__(256) void kv_reduce_k(const float* __restrict__ kvp,
                                                   const float* __restrict__ kmp,
                                                   unsigned short* __restrict__ kvT,
                                                   float* __restrict__ km) {
  const int tid = threadIdx.x;
  const int bx = blockIdx.x;
  if (bx < 24) {
    __shared__ float t[64 * 65];
    float acc[16] = {};
    const float* base = kvp + (size_t)bx * 4096 + tid * 16;
    for (int c = 0; c < KVCH; ++c) {
      const float* p = base + (size_t)c * 24 * 4096;
      #pragma unroll
      for (int i = 0; i < 4; ++i) {
        float4 v = *(const float4*)(p + i * 4);
        acc[i * 4 + 0] += v.x; acc[i * 4 + 1] += v.y; acc[i * 4 + 2] += v.z; acc[i * 4 + 3] += v.w;
      }
    }
    const int d = tid >> 2, e0 = (tid & 3) * 16;   // writes row d, cols e0..e0+15
    #pragma unroll
    for (int i = 0; i < 16; ++i) t[d * 65 + e0 + i] = acc[i] * (1.f / NM_);
    __syncthreads();
    const int e = tid >> 2, dd0 = (tid & 3) * 16;  // read col e, rows dd0..+15
    ushort4 o[4];
    #pragma unroll
    for (int i = 0; i < 16; ++i)
      ((unsigned short*)o)[i] = bf16r(t[(dd0 + i) * 65 + e]);
    unsigned short* dst = kvT + (size_t)bx * 4096 + e * 64 + dd0;
    *(ushort4*)(dst) = o[0]; *(ushort4*)(dst + 4) = o[1];
    *(ushort4*)(dst + 8) = o[2]; *(ushort4*)(dst + 12) = o[3];
  } else {
    int i = (bx - 24) * 256 + tid;                 // 6 blocks cover 1536 outputs
    if (i < 24 * 64) {
      int bhh = i >> 6, d = i & 63;
      float s = 0.f;
      for (int c = 0; c < KVCH; ++c) s += kmp[((size_t)c * 24 + bhh) * 64 + d];
      int b = bhh / NHEAD, h = bhh % NHEAD;
      km[b * CD + h * 64 + d] = s * (1.f / NM_);
    }
  }
}

// -------- depthwise 5x5 conv, LDS-tiled: block = (b,h) x 16-wide x-tile ------
__global__ __launch_bounds__(256) void dwconv_k(const unsigned short* __restrict__ Vp,
                                                const float* __restrict__ w,
                                                const float* __restrict__ bias,
                                                unsigned short* __restrict__ outp) {
  __shared__ __align__(16) unsigned ls32[16 * 20 * 32];  // ushort2-packed channels
  __shared__ float wsm[64 * 25];
  __shared__ float bsm[64];
  const int tid = threadIdx.x;
  const int bh = blockIdx.x, b = bh / NHEAD, h = bh % NHEAD;
  const int x0 = blockIdx.y * 16;
  for (int i = tid; i < 1600; i += 256) wsm[i] = w[i];
  if (tid < 64) bsm[tid] = bias[tid];
  const int lch = (tid & 7) * 8;
  #pragma unroll
  for (int it = 0; it < 10; ++it) {
    int p = it * 32 + (tid >> 3);
    int y = p / 20, xp = p % 20;
    int xx = x0 + xp - 2;
    int4 val = {0, 0, 0, 0};
    if (xx >= 0 && xx < 256)
      val = *(const int4*)(Vp + ((size_t)((y << 8) + xx) * BSZ + b) * CD + h * 64 + lch);
    *(int4*)((unsigned short*)ls32 + p * 64 + lch) = val;
  }
  __syncthreads();
  const int cp = tid & 31;        // channel pair: ch = {2cp, 2cp+1}
  const int xs = tid >> 5;        // 0..7 -> x outputs {2xs, 2xs+1}
  float wr0[25], wr1[25];
  #pragma unroll
  for (int t = 0; t < 25; ++t) { wr0[t] = wsm[(cp * 2) * 25 + t]; wr1[t] = wsm[(cp * 2 + 1) * 25 + t]; }
  const float b0 = bsm[cp * 2], b1 = bsm[cp * 2 + 1];
  for (int y = 0; y < 16; ++y) {
    float a00 = b0, a01 = b1, a10 = b0, a11 = b1;
    #pragma unroll
    for (int dy = 0; dy < 5; ++dy) {
      int yy = y + dy - 2;
      if (yy < 0 || yy >= 16) continue;
      #pragma unroll
      for (int dx = 0; dx < 5; ++dx) {
        int base = (yy * 20 + xs * 2 + dx) * 32 + cp;
        unsigned u0 = ls32[base], u1 = ls32[base + 32];
        float w0 = wr0[dy * 5 + dx], w1 = wr1[dy * 5 + dx];
        a00 += w0 * asf(u0 << 16);  a01 += w1 * asf(u0 & 0xffff0000u);
        a10 += w0 * asf(u1 << 16);  a11 += w1 * asf(u1 & 0xffff0000u);
      }
    }
    const int x = x0 + xs * 2;
    size_t o = ((size_t)((y << 8) + x) * BSZ + b) * CD + h * 64 + cp * 2;
    ushort2 s0; s0.x = bf16r(a00); s0.y = bf16r(a01);
    ushort2 s1; s1.x = bf16r(a10); s1.y = bf16r(a11);
    *(ushort2*)(outp + o) = s0;
    *(ushort2*)(outp + o + (size_t)BSZ * CD) = s1;
  }
}

// ------ attn: tmp = bf16( z * (q @ kv) + dwc ), MFMA per head, K=64 ---------
__global__ __launch_bounds__(256) void attn_mfma(const unsigned short* __restrict__ Qb,
                                                 const unsigned short* __restrict__ kvT,
                                                 const float* __restrict__ km,
                                                 const unsigned short* __restrict__ dwcb,
                                                 unsigned short* __restrict__ tmpb) {
  __shared__ __align__(16) unsigned short qs[128 * 64];
  __shared__ __align__(16) unsigned short kvs[64 * 64];
  __shared__ float kms[64];
  __shared__ float zs[128];
  const int bh = blockIdx.x, b = bh / NHEAD, h = bh % NHEAD;
  const int n0 = blockIdx.y * 128;
  const int tid = threadIdx.x, wave = tid >> 6, lane = tid & 63;
  const int quad = lane >> 4, l16 = lane & 15;
  #pragma unroll
  for (int c2 = 0; c2 < 4; ++c2) {
    int ch = wave * 4 + c2;
    int row = ch * 8 + (lane >> 3);
    int col = (lane & 7) * 8;
    gl2lds16(Qb + ((size_t)(n0 + row) * BSZ + b) * KSTR + h * 64 + col, (void*)(qs + ch * 512));
  }
  #pragma unroll
  for (int c2 = 0; c2 < 2; ++c2) {
    int ch = wave * 2 + c2;
    int e = ch * 8 + (lane >> 3);
    int col = (lane & 7) * 8;
    gl2lds16(kvT + (size_t)bh * 4096 + e * 64 + col, (void*)(kvs + ch * 512));
  }
  if (tid < 64) kms[tid] = km[b * CD + h * 64 + tid];
  __syncthreads();
  if (tid < 128) {
    float s = 0.f;
    for (int d2 = 0; d2 < 64; ++d2) s += b2f(qs[tid * 64 + d2]) * kms[d2];
    zs[tid] = 1.f / (s + EPSF);
  }
  __syncthreads();
  f32x4 acc[2][4] = {};
  #pragma unroll
  for (int kh = 0; kh < 2; ++kh) {
    bf16x8 a0 = *(const bf16x8*)(qs + (wave * 32 + l16) * 64 + kh * 32 + quad * 8);
    bf16x8 a1 = *(const bf16x8*)(qs + (wave * 32 + 16 + l16) * 64 + kh * 32 + quad * 8);
    bf16x8 bt[4];
    #pragma unroll
    for (int tn = 0; tn < 4; ++tn)
      bt[tn] = *(const bf16x8*)(kvs + (tn * 16 + l16) * 64 + kh * 32 + quad * 8);
    #pragma unroll
    for (int tn = 0; tn < 4; ++tn) {
      acc[0][tn] = __builtin_amdgcn_mfma_f32_16x16x32_bf16(a0, bt[tn], acc[0][tn], 0, 0, 0);
      acc[1][tn] = __builtin_amdgcn_mfma_f32_16x16x32_bf16(a1, bt[tn], acc[1][tn], 0, 0, 0);
    }
  }
  #pragma unroll
  for (int tm = 0; tm < 2; ++tm)
    #pragma unroll
    for (int tn = 0; tn < 4; ++tn)
      #pragma unroll
      for (int r = 0; r < 4; ++r) {
        int rl = wave * 32 + tm * 16 + quad * 4 + r;
        int n = n0 + rl;
        int m = n & (NM_ - 1);
        int c = h * 64 + tn * 16 + l16;
        float val = acc[tm][tn][r] * zs[rl] + b2f(dwcb[((size_t)m * BSZ + b) * CD + c]);
        tmpb[((size_t)n * BSZ + b) * CD + c] = bf16r(val);
      }
}

// =============================== launcher ===============================
extern "C" void kernel_launch(void* const* d_in, const int* in_sizes, int n_in,
                              void* d_out, int out_size, void* d_ws, size_t ws_size,
                              hipStream_t stream) {
  const float* x      = (const float*)d_in[0];
  const float* memory = (const float*)d_in[1];
  const float* w_q    = (const float*)d_in[2];
  const float* w_k    = (const float*)d_in[3];
  const float* w_v    = (const float*)d_in[4];
  const float* w_proj = (const float*)d_in[5];
  const float* b_proj = (const float*)d_in[6];
  const float* dwc_w  = (const float*)d_in[7];
  const float* dwc_b  = (const float*)d_in[8];
  const float* scale  = (const float*)d_in[9];
  float* out = (float*)d_out;

  const int Mq = NX_ * BSZ;   // 32768
  const int Mm = NM_ * BSZ;   // 8192

  char* ws = (char*)d_ws;
  size_t off = 0;
  auto alloc = [&](size_t bytes) -> void* {
    void* p = ws + off;
    off += (bytes + 255) & ~(size_t)255;
    return p;
  };
  float* q    = (float*)alloc((size_t)Mq * CD * 4);   // fp32, later bf16 in-place (stride KSTR)
  float* kbuf = (float*)alloc((size_t)Mm * CD * 4);   // fp32, later bf16 in-place
  float* kvp  = (float*)alloc((size_t)KVCH * 24 * 4096 * 4);   // 12.6 MB partials
  float* kmp  = (float*)alloc((size_t)KVCH * 24 * 64 * 4);
  float* km   = (float*)alloc((size_t)BSZ * CD * 4);
  float* sp   = (float*)alloc(CD * 4);
  unsigned short* tmpb = (unsigned short*)alloc((size_t)Mq * CD * 2);
  unsigned short* vb   = (unsigned short*)alloc((size_t)Mm * CD * 2);  // bf16 v
  unsigned short* dwcb = (unsigned short*)alloc((size_t)Mm * CD * 2);
  unsigned short* kvT  = (unsigned short*)alloc((size_t)BSZ * NHEAD * DH * DH * 2);
  unsigned short* wqb  = (unsigned short*)alloc((size_t)CD * CD * 2);
  unsigned short* wkb  = (unsigned short*)alloc((size_t)CD * CD * 2);
  unsigned short* wvb  = (unsigned short*)alloc((size_t)CD * CD * 2);
  unsigned short* wpb  = (unsigned short*)alloc((size_t)CD * CD * 2);

  // buffer reuse (lifetimes checked): xb lives in tmpb until attn_mfma writes it;
  // memb lives in dwcb until dwconv_k writes it (k/v gemms read memb before that).
  unsigned short* xb   = tmpb;
  unsigned short* memb = dwcb;

  prep_k<<<2307, 256, 0, stream>>>(w_q, w_k, w_v, w_proj, scale, wqb, wkb, wvb, wpb, sp);

  cvt_k<<<(Mq * CD / 8 + 255) / 256, 256, 0, stream>>>(x, xb, Mq * CD / 8);
  cvt_k<<<(Mm * CD / 8 + 255) / 256, 256, 0, stream>>>(memory, memb, Mm * CD / 8);

  gemm8p<0><<<dim3(Mq / 256, CD / 256), 512, 0, stream>>>(xb, wqb, q, nullptr, Mq, CD);
  gemm128<0><<<dim3(Mm / 128, CD / 128), 256, 0, stream>>>(memb, wkb, kbuf, nullptr, Mm, CD, CD);
  gemm128<1><<<dim3(Mm / 128, CD / 128), 256, 0, stream>>>(memb, wvb, vb,   nullptr, Mm, CD, CD);

  process_rows<<<Mq, 256, 0, stream>>>(q, sp);     // q -> bf16 in-place
  process_rows<<<Mm, 256, 0, stream>>>(kbuf, sp);  // k -> bf16 in-place

  const unsigned short* qb = (const unsigned short*)q;
  const unsigned short* kb = (const unsigned short*)kbuf;

  kv_part_k<<<dim3(24, KVCH), 256, 0, stream>>>(kb, vb, kvp, kmp);
  kv_reduce_k<<<30, 256, 0, stream>>>(kvp, kmp, kvT, km);

  dwconv_k<<<dim3(BSZ * NHEAD, 16), 256, 0, stream>>>(vb, dwc_w, dwc_b, dwcb);

  attn_mfma<<<dim3(BSZ * NHEAD, NX_ / 128), 256, 0, stream>>>(qb, kvT, km, dwcb, tmpb);

  gemm8p<0><<<dim3(Mq / 256, CD / 256), 512, 0, stream>>>(tmpb, wpb, out, b_proj, Mq, CD);
}